// Round 12
// baseline (111.944 us; speedup 1.0000x reference)
//
#include <hip/hip_runtime.h>
#include <hip/hip_bf16.h>
#include <math.h>

// Problem constants (from the reference)
#define BB 512        // batch
#define CC 1000       // classes
#define TT 64         // num param tensors
#define PSZ 500000    // elements per tensor
#define NW 9          // loss weights per tensor

#define NF4_T 125000  // float4 per tensor
#define PB 500        // param blocks; PB*256 = 128000 threads >= NF4_T

// Workspace layout (floats):
//  ws[0] = sum_b CE contribution    ws[1] = sum_b hinge row sums
//  ws[2] = sum_{b,j} logp           ws[3] = sum_b sum_j p*logp
//  ws[4] = sum_{b,j} o^2
//  ws[8 + t*4 + {0,1,2,3}] = {l1_zero, sumsq_zero, l1_pre, sumsq_pre}
#define WS_FLOATS (8 + TT * 4)

typedef float f32x4 __attribute__((ext_vector_type(4)));

__device__ __forceinline__ f32x4 ntload(const f32x4* a) {
    return __builtin_nontemporal_load(a);
}

// ---------------------------------------------------------------------------
__device__ __forceinline__ float block_reduce_sum(float v, float* scratch) {
    __syncthreads();
    for (int o = 32; o > 0; o >>= 1) v += __shfl_down(v, o);
    const int wave = threadIdx.x >> 6;
    if ((threadIdx.x & 63) == 0) scratch[wave] = v;
    __syncthreads();
    return scratch[0] + scratch[1] + scratch[2] + scratch[3];
}

__device__ __forceinline__ float block_reduce_max(float v, float* scratch) {
    __syncthreads();
    for (int o = 32; o > 0; o >>= 1) v = fmaxf(v, __shfl_down(v, o));
    const int wave = threadIdx.x >> 6;
    if ((threadIdx.x & 63) == 0) scratch[wave] = v;
    __syncthreads();
    return fmaxf(fmaxf(scratch[0], scratch[1]), fmaxf(scratch[2], scratch[3]));
}

__device__ __forceinline__ void acc4(const f32x4 a, const f32x4 c,
                                     float& l1z, float& s2z,
                                     float& l1p, float& s2p) {
    l1z += fabsf(a.x) + fabsf(a.y) + fabsf(a.z) + fabsf(a.w);
    s2z += a.x * a.x + a.y * a.y + a.z * a.z + a.w * a.w;
    const float dx = a.x - c.x, dy = a.y - c.y, dz = a.z - c.z, dw = a.w - c.w;
    l1p += fabsf(dx) + fabsf(dy) + fabsf(dz) + fabsf(dw);
    s2p += dx * dx + dy * dy + dz * dz + dw * dw;
}

// ---------------------------------------------------------------------------
// Fused kernel.
// Param path (blocks [0,500)): LOCKSTEP TENSOR-MAJOR SWEEP. The whole param
// grid (128000 threads) covers one tensor (125000 f4); iterate t=0..63 with
// every thread loading p4[t*NF4_T+g] and q4[t*NF4_T+g]. At any instant the
// machine's outstanding reads live in two ~2 MB ascending windows — the
// copy-kernel pattern (m13, 6.3 TB/s) — vs R7's 1280 streams scattered over
// 256 MB. No barriers/atomics in the loop: t is grid-uniform per step, so
// per-step wave-reduce (24 shfl / 2 KB) accumulates into per-wave LDS slots;
// depth-2 register prefetch covers HBM latency.
// Logits path: blocks [500, 1012).
// ---------------------------------------------------------------------------
__global__ __launch_bounds__(256) void fused_kernel(
        const float* __restrict__ p, const float* __restrict__ q,
        const float* __restrict__ outlog, const int* __restrict__ tgt,
        float* __restrict__ ws) {
    __shared__ float row[CC];
    __shared__ float scratch[4];
    __shared__ float acc_lds[4][TT][4];   // [wave][tensor][term], 4 KB

    const int bid = blockIdx.x;
    const int tid = (int)threadIdx.x;

    if (bid < PB) {
        // ---------------- param-norm path (256 MB total) -------------------
        const int g    = bid * 256 + tid;      // 0..127999; active if < NF4_T
        const bool act = g < NF4_T;
        const int wave = tid >> 6;
        const int lane = tid & 63;

        // zero this block's accumulator slots, once
        float* fl = &acc_lds[0][0][0];
        fl[tid] = 0.f; fl[tid + 256] = 0.f; fl[tid + 512] = 0.f; fl[tid + 768] = 0.f;
        __syncthreads();

        const f32x4* __restrict__ p4 = (const f32x4*)p;
        const f32x4* __restrict__ q4 = (const f32x4*)q;

        f32x4 z; z.x = 0.f; z.y = 0.f; z.z = 0.f; z.w = 0.f;

        // depth-2 prefetch: pairs for t=0 and t=1 in flight
        f32x4 a0 = act ? ntload(p4 + g) : z;
        f32x4 c0 = act ? ntload(q4 + g) : z;
        f32x4 a1 = act ? ntload(p4 + NF4_T + g) : z;
        f32x4 c1 = act ? ntload(q4 + NF4_T + g) : z;

        #pragma unroll 1
        for (int t = 0; t < TT; ++t) {
            // issue prefetch for t+2
            f32x4 an = z, cn = z;
            if (t + 2 < TT && act) {
                const long long base = (long long)(t + 2) * NF4_T + g;
                an = ntload(p4 + base);
                cn = ntload(q4 + base);
            }

            float l1z = 0.f, s2z = 0.f, l1p = 0.f, s2p = 0.f;
            acc4(a0, c0, l1z, s2z, l1p, s2p);   // inactive lanes: zeros

            a0 = a1; c0 = c1; a1 = an; c1 = cn;

            // wave-reduce the 4 partials (all 64 lanes participate)
            for (int o = 32; o > 0; o >>= 1) {
                l1z += __shfl_down(l1z, o);
                s2z += __shfl_down(s2z, o);
                l1p += __shfl_down(l1p, o);
                s2p += __shfl_down(s2p, o);
            }
            if (lane == 0) {
                float* s = &acc_lds[wave][t][0];
                s[0] += l1z; s[1] += s2z; s[2] += l1p; s[3] += s2p;
            }
        }

        __syncthreads();
        // epilogue: tid = t*4+k exactly matches ws[8+tid] layout
        const int tt = tid >> 2, kk = tid & 3;
        const float v = acc_lds[0][tt][kk] + acc_lds[1][tt][kk]
                      + acc_lds[2][tt][kk] + acc_lds[3][tt][kk];
        atomicAdd(ws + 8 + tid, v);
    } else {
        // ---------------- logits path (one block per batch row) ------------
        const int b = bid - PB;
        const float* __restrict__ o = outlog + (long long)b * CC;

        float sq = 0.f;
        for (int j = tid; j < CC; j += 256) {
            const float v = o[j];
            row[j] = v;
            sq += v * v;
        }
        __syncthreads();

        float m = -3.402823466e+38f;
        for (int j = tid; j < CC; j += 256) m = fmaxf(m, row[j]);
        m = block_reduce_max(m, scratch);

        float se = 0.f;
        for (int j = tid; j < CC; j += 256) se += __expf(row[j] - m);
        se = block_reduce_sum(se, scratch);
        const float logZ = m + __logf(se);

        const int tg = tgt[b];
        const float ot = row[tg];

        float ent = 0.f, lps = 0.f, hin = 0.f;
        for (int j = tid; j < CC; j += 256) {
            const float lp = row[j] - logZ;
            ent += __expf(lp) * lp;
            lps += lp;
            const float mg = 1.f - ot + row[j];
            if (j != tg && mg > 0.f) hin += mg;
        }
        sq  = block_reduce_sum(sq, scratch);
        ent = block_reduce_sum(ent, scratch);
        lps = block_reduce_sum(lps, scratch);
        hin = block_reduce_sum(hin, scratch);

        if (tid == 0) {
            atomicAdd(&ws[0], -(ot - logZ));
            atomicAdd(&ws[1], hin);
            atomicAdd(&ws[2], lps);
            atomicAdd(&ws[3], ent);
            atomicAdd(&ws[4], sq);
        }
    }
}

// ---------------------------------------------------------------------------
// Final combine — 64x9 sigmoid-weighted sum, one block
// ---------------------------------------------------------------------------
__global__ __launch_bounds__(256) void final_kernel(
        const float* __restrict__ lw, const float* __restrict__ ws,
        float* __restrict__ out) {
    __shared__ float scratch[4];
    const float ce      = ws[0] / (float)BB;
    const float hinge   = ws[1] / ((float)BB * (float)CC);
    const float kl      = -logf((float)CC) - ws[2] / ((float)BB * (float)CC);
    const float entropy = -ws[3] / (float)BB;
    const float energy  = sqrtf(ws[4]);
    const float glob[5] = {ce, hinge, kl, entropy, energy};

    float acc = 0.f;
    for (int i = threadIdx.x; i < TT * NW; i += 256) {
        const int t = i / NW;
        const int k = i - t * NW;
        float cmb;
        if (k < 5)       cmb = glob[k];
        else if (k == 5) cmb = ws[8 + t * 4 + 0];
        else if (k == 6) cmb = sqrtf(ws[8 + t * 4 + 1]);
        else if (k == 7) cmb = ws[8 + t * 4 + 2];
        else             cmb = sqrtf(ws[8 + t * 4 + 3]);
        const float w = 1.f / (1.f + expf(-lw[i]));
        acc += w * cmb;
    }
    acc = block_reduce_sum(acc, scratch);
    if (threadIdx.x == 0) out[0] = acc / (float)(TT * NW);
}

// ---------------------------------------------------------------------------
extern "C" void kernel_launch(void* const* d_in, const int* in_sizes, int n_in,
                              void* d_out, int out_size, void* d_ws, size_t ws_size,
                              hipStream_t stream) {
    const float* outputs    = (const float*)d_in[0];
    const int*   targets    = (const int*)d_in[1];
    const float* params     = (const float*)d_in[2];
    const float* pretrained = (const float*)d_in[3];
    const float* lw         = (const float*)d_in[4];
    float* ws  = (float*)d_ws;
    float* out = (float*)d_out;

    hipMemsetAsync(ws, 0, WS_FLOATS * sizeof(float), stream);

    // 500 lockstep param blocks + 512 logits blocks
    fused_kernel<<<PB + BB, 256, 0, stream>>>(params, pretrained, outputs, targets, ws);
    final_kernel<<<1, 256, 0, stream>>>(lw, ws, out);
}